// Round 3
// baseline (558.277 us; speedup 1.0000x reference)
//
#include <hip/hip_runtime.h>
#include <hip/hip_bf16.h>

#define B_ 8
#define C_ 64
#define H_ 128
#define W_ 128
#define HW_ (H_ * W_)

static __device__ inline unsigned short bfbits(float f) {
    __hip_bfloat16 h = __float2bfloat16(f);
    unsigned short s;
    __builtin_memcpy(&s, &h, 2);
    return s;
}
static __device__ inline float bf_lo(unsigned u) { return __uint_as_float(u << 16); }
static __device__ inline float bf_hi(unsigned u) { return __uint_as_float(u & 0xffff0000u); }

// ---------------------------------------------------------------------------
// K1: QKV 1x1-conv projection. Thread = pixel, block = one 16-out-ch chunk.
// grid (HW/256=64, 4 chunks, B), block 256, launch_bounds(256,2) so xv[64]
// stays in VGPRs (R2's 64-VGPR cap spilled it to scratch -> 140 us).
// q,k fp32 ws layout [B][4][HW][16]; v bf16 ws layout [B][4][HW][16].
// ---------------------------------------------------------------------------
__global__ __launch_bounds__(256, 2) void proj_qkv(
    const float* __restrict__ x, const float* __restrict__ w1,
    const float* __restrict__ w2, const float* __restrict__ w3,
    float* __restrict__ q, float* __restrict__ k, unsigned short* __restrict__ v)
{
    const int px = blockIdx.x * 256 + threadIdx.x;
    const int chunk = blockIdx.y;
    const int b = blockIdx.z;
    const float* xb = x + (size_t)b * C_ * HW_ + px;

    float xv[64];
    #pragma unroll
    for (int c = 0; c < 64; ++c) xv[c] = xb[(size_t)c * HW_];

    float oq[16], ok[16], ov[16];
    #pragma unroll 2
    for (int oi = 0; oi < 16; ++oi) {
        const int o = chunk * 16 + oi;
        const float* __restrict__ r1 = w1 + o * 64;
        const float* __restrict__ r2 = w2 + o * 64;
        const float* __restrict__ r3 = w3 + o * 64;
        float aq0 = 0.f, aq1 = 0.f, ak0 = 0.f, ak1 = 0.f, av0 = 0.f, av1 = 0.f;
        #pragma unroll
        for (int c = 0; c < 64; c += 2) {
            aq0 += r1[c]     * xv[c];
            aq1 += r1[c + 1] * xv[c + 1];
            ak0 += r2[c]     * xv[c];
            ak1 += r2[c + 1] * xv[c + 1];
            av0 += r3[c]     * xv[c];
            av1 += r3[c + 1] * xv[c + 1];
        }
        oq[oi] = aq0 + aq1;
        ok[oi] = ak0 + ak1;
        ov[oi] = av0 + av1;
    }

    const size_t base = (((size_t)b * 4 + chunk) * HW_ + px) * 16;
    #pragma unroll
    for (int j = 0; j < 4; ++j) {
        *(float4*)(q + base + j * 4) =
            make_float4(oq[j*4], oq[j*4+1], oq[j*4+2], oq[j*4+3]);
        *(float4*)(k + base + j * 4) =
            make_float4(ok[j*4], ok[j*4+1], ok[j*4+2], ok[j*4+3]);
    }
    unsigned vb[8];
    #pragma unroll
    for (int j = 0; j < 8; ++j)
        vb[j] = (unsigned)bfbits(ov[2*j]) | ((unsigned)bfbits(ov[2*j+1]) << 16);
    uint4* vp = (uint4*)(v + base);
    vp[0] = make_uint4(vb[0], vb[1], vb[2], vb[3]);
    vp[1] = make_uint4(vb[4], vb[5], vb[6], vb[7]);
}

// ---------------------------------------------------------------------------
// K2: fused local attention. Tile 8h x 32w, block 128 threads, each thread
// owns 2 w-adjacent pixels (window union 7x8=56 -> 1.75x fewer LDS reads).
// Halo 14x38=532 px. LDS plane-major, plane stride 532*4+8=2136 words
// (bases mod 32 = {0,24,16,8}); compute reads lane-stride 4 words = free
// 2-way. Phase 1 K fp32 (4 planes); phase 2 V bf16 (2 planes, halved reads).
// launch_bounds(128,2): 256-VGPR cap keeps sc0[49]+sc1[49] in registers.
// grid (4, 16, 8) = 512 blocks. LDS 33.4 KB -> 4 blocks/CU.
// ---------------------------------------------------------------------------
#define HR_ 14
#define HC_ 38
#define HP_ (HR_ * HC_)          // 532 halo pixels
#define PLANE_ (HP_ * 4 + 8)     // 2136 words per plane

__global__ __launch_bounds__(128, 2) void local_attn(
    const float* __restrict__ q, const float* __restrict__ k,
    const unsigned short* __restrict__ v, float* __restrict__ out)
{
    __shared__ float tile[4 * PLANE_];
    const int b = blockIdx.z, h0 = blockIdx.y * 8, w0 = blockIdx.x * 32;
    const int t = threadIdx.x;
    const int pwb = t & 15, ph = t >> 4;   // pixel pair column, row
    const int wl = pwb * 2;                // tile-local w of first pixel

    float sc0[49], sc1[49];
    #pragma unroll
    for (int i = 0; i < 49; ++i) { sc0[i] = 0.f; sc1[i] = 0.f; }

    // ---- phase 1: scores (K fp32 in LDS) ----
    for (int chunk = 0; chunk < 4; ++chunk) {
        const float* kc = k + ((size_t)b * 4 + chunk) * HW_ * 16;
        for (int i = t; i < HP_ * 4; i += 128) {
            const int pix = i >> 2, c4 = i & 3;
            const int r = pix / HC_, cl = pix - r * HC_;
            const int gh = h0 + r - 3, gw = w0 + cl - 3;
            float4 val = make_float4(0.f, 0.f, 0.f, 0.f);
            if (gh >= 0 && gh < H_ && gw >= 0 && gw < W_)
                val = *(const float4*)(kc + ((size_t)gh * W_ + gw) * 16 + c4 * 4);
            *(float4*)(tile + c4 * PLANE_ + pix * 4) = val;
        }
        const float* qp = q + (((size_t)b * 4 + chunk) * HW_ +
                               (size_t)(h0 + ph) * W_ + (w0 + wl)) * 16;
        const float4 qa0 = ((const float4*)qp)[0];
        const float4 qa1 = ((const float4*)qp)[1];
        const float4 qa2 = ((const float4*)qp)[2];
        const float4 qa3 = ((const float4*)qp)[3];
        const float4 qb0 = ((const float4*)qp)[4];  // second pixel (+16 floats)
        const float4 qb1 = ((const float4*)qp)[5];
        const float4 qb2 = ((const float4*)qp)[6];
        const float4 qb3 = ((const float4*)qp)[7];
        __syncthreads();
        #pragma unroll
        for (int dh = 0; dh < 7; ++dh) {
            #pragma unroll
            for (int j = 0; j < 8; ++j) {
                const int np = ((ph + dh) * HC_ + (wl + j)) * 4;
                const float4 k0 = *(const float4*)(tile + 0 * PLANE_ + np);
                const float4 k1 = *(const float4*)(tile + 1 * PLANE_ + np);
                const float4 k2 = *(const float4*)(tile + 2 * PLANE_ + np);
                const float4 k3 = *(const float4*)(tile + 3 * PLANE_ + np);
                if (j < 7)
                    sc0[dh * 7 + j] +=
                        qa0.x*k0.x + qa0.y*k0.y + qa0.z*k0.z + qa0.w*k0.w +
                        qa1.x*k1.x + qa1.y*k1.y + qa1.z*k1.z + qa1.w*k1.w +
                        qa2.x*k2.x + qa2.y*k2.y + qa2.z*k2.z + qa2.w*k2.w +
                        qa3.x*k3.x + qa3.y*k3.y + qa3.z*k3.z + qa3.w*k3.w;
                if (j > 0)
                    sc1[dh * 7 + j - 1] +=
                        qb0.x*k0.x + qb0.y*k0.y + qb0.z*k0.z + qb0.w*k0.w +
                        qb1.x*k1.x + qb1.y*k1.y + qb1.z*k1.z + qb1.w*k1.w +
                        qb2.x*k2.x + qb2.y*k2.y + qb2.z*k2.z + qb2.w*k2.w +
                        qb3.x*k3.x + qb3.y*k3.y + qb3.z*k3.z + qb3.w*k3.w;
            }
        }
        __syncthreads();
    }

    // ---- softmax over 49, per pixel ----
    {
        float m0 = sc0[0], m1 = sc1[0];
        #pragma unroll
        for (int i = 1; i < 49; ++i) { m0 = fmaxf(m0, sc0[i]); m1 = fmaxf(m1, sc1[i]); }
        float s0 = 0.f, s1 = 0.f;
        #pragma unroll
        for (int i = 0; i < 49; ++i) {
            sc0[i] = __expf(sc0[i] - m0); s0 += sc0[i];
            sc1[i] = __expf(sc1[i] - m1); s1 += sc1[i];
        }
        const float i0 = 1.f / s0, i1 = 1.f / s1;
        #pragma unroll
        for (int i = 0; i < 49; ++i) { sc0[i] *= i0; sc1[i] *= i1; }
    }

    // ---- phase 2: weighting (V bf16 in LDS, 2 planes of 8ch) ----
    for (int chunk = 0; chunk < 4; ++chunk) {
        const unsigned short* vc = v + ((size_t)b * 4 + chunk) * HW_ * 16;
        for (int i = t; i < HP_ * 2; i += 128) {
            const int pix = i >> 1, c8 = i & 1;
            const int r = pix / HC_, cl = pix - r * HC_;
            const int gh = h0 + r - 3, gw = w0 + cl - 3;
            uint4 val = make_uint4(0u, 0u, 0u, 0u);
            if (gh >= 0 && gh < H_ && gw >= 0 && gw < W_)
                val = *(const uint4*)(vc + ((size_t)gh * W_ + gw) * 16 + c8 * 8);
            *(uint4*)(tile + c8 * PLANE_ + pix * 4) = val;
        }
        __syncthreads();
        float acc0[16], acc1[16];
        #pragma unroll
        for (int c = 0; c < 16; ++c) { acc0[c] = 0.f; acc1[c] = 0.f; }
        #pragma unroll
        for (int dh = 0; dh < 7; ++dh) {
            #pragma unroll
            for (int j = 0; j < 8; ++j) {
                const int np = ((ph + dh) * HC_ + (wl + j)) * 4;
                const uint4 u0 = *(const uint4*)(tile + 0 * PLANE_ + np);
                const uint4 u1 = *(const uint4*)(tile + 1 * PLANE_ + np);
                const float wA = (j < 7) ? sc0[dh * 7 + j] : 0.f;
                const float wB = (j > 0) ? sc1[dh * 7 + j - 1] : 0.f;
                float f[16];
                f[0] = bf_lo(u0.x); f[1] = bf_hi(u0.x);
                f[2] = bf_lo(u0.y); f[3] = bf_hi(u0.y);
                f[4] = bf_lo(u0.z); f[5] = bf_hi(u0.z);
                f[6] = bf_lo(u0.w); f[7] = bf_hi(u0.w);
                f[8]  = bf_lo(u1.x); f[9]  = bf_hi(u1.x);
                f[10] = bf_lo(u1.y); f[11] = bf_hi(u1.y);
                f[12] = bf_lo(u1.z); f[13] = bf_hi(u1.z);
                f[14] = bf_lo(u1.w); f[15] = bf_hi(u1.w);
                #pragma unroll
                for (int c = 0; c < 16; ++c) {
                    acc0[c] += wA * f[c];
                    acc1[c] += wB * f[c];
                }
            }
        }
        // out [B][64][H][W]; thread owns 2 consecutive w -> float2 stores
        const size_t ob = ((size_t)b * 64 + chunk * 16) * HW_ +
                          (size_t)(h0 + ph) * W_ + (w0 + wl);
        #pragma unroll
        for (int c = 0; c < 16; ++c)
            *(float2*)(out + ob + (size_t)c * HW_) = make_float2(acc0[c], acc1[c]);
        __syncthreads();
    }
}

extern "C" void kernel_launch(void* const* d_in, const int* in_sizes, int n_in,
                              void* d_out, int out_size, void* d_ws, size_t ws_size,
                              hipStream_t stream) {
    const float* x  = (const float*)d_in[0];
    const float* w1 = (const float*)d_in[1];
    const float* w2 = (const float*)d_in[2];
    const float* w3 = (const float*)d_in[3];

    const size_t NE = (size_t)B_ * 4 * HW_ * 16;  // 8388608 elements
    float* q = (float*)d_ws;
    float* k = q + NE;
    unsigned short* v = (unsigned short*)(k + NE);
    float* o = (float*)d_out;

    proj_qkv<<<dim3(HW_ / 256, 4, B_), 256, 0, stream>>>(x, w1, w2, w3, q, k, v);
    local_attn<<<dim3(W_ / 32, H_ / 8, B_), 128, 0, stream>>>(q, k, v, o);
}

// Round 4
// 234.783 us; speedup vs baseline: 2.3778x; 2.3778x over previous
//
#include <hip/hip_runtime.h>
#include <hip/hip_bf16.h>

#define B_ 8
#define C_ 64
#define H_ 128
#define W_ 128
#define HW_ (H_ * W_)

static __device__ inline unsigned short bfbits(float f) {
    __hip_bfloat16 h = __float2bfloat16(f);
    unsigned short s;
    __builtin_memcpy(&s, &h, 2);
    return s;
}
static __device__ inline float bf_lo(unsigned u) { return __uint_as_float(u << 16); }
static __device__ inline float bf_hi(unsigned u) { return __uint_as_float(u & 0xffff0000u); }

// ---------------------------------------------------------------------------
// K1: QKV 1x1-conv projection. Thread = pixel, computes ALL 64 out-ch
// (4 chunks of 16). x loaded in two halves of 32 so peak live VGPRs ~95
// (32 xv + 48 acc + temps) -- no spills even at a 128-reg allocation.
// Chunks >0 re-read x from L1/L2 (block footprint 64 KB).
// q,k fp32 [B][4][HW][16]; v bf16 [B][4][HW][16].
// grid (HW/256=64, B), block 256.
// ---------------------------------------------------------------------------
__global__ __launch_bounds__(256, 2) void proj_qkv(
    const float* __restrict__ x, const float* __restrict__ w1,
    const float* __restrict__ w2, const float* __restrict__ w3,
    float* __restrict__ q, float* __restrict__ k, unsigned short* __restrict__ v)
{
    const int px = blockIdx.x * 256 + threadIdx.x;
    const int b  = blockIdx.y;
    const float* xb = x + (size_t)b * C_ * HW_ + px;

    for (int chunk = 0; chunk < 4; ++chunk) {
        float oq[16], ok[16], ov[16];
        #pragma unroll
        for (int i = 0; i < 16; ++i) { oq[i] = 0.f; ok[i] = 0.f; ov[i] = 0.f; }

        #pragma unroll
        for (int half = 0; half < 2; ++half) {
            float xv[32];
            #pragma unroll
            for (int c = 0; c < 32; ++c)
                xv[c] = xb[(size_t)(half * 32 + c) * HW_];

            #pragma unroll 4
            for (int oi = 0; oi < 16; ++oi) {
                const int o = chunk * 16 + oi;
                const float* __restrict__ r1 = w1 + o * 64 + half * 32;
                const float* __restrict__ r2 = w2 + o * 64 + half * 32;
                const float* __restrict__ r3 = w3 + o * 64 + half * 32;
                float aq0 = 0.f, aq1 = 0.f, ak0 = 0.f, ak1 = 0.f, av0 = 0.f, av1 = 0.f;
                #pragma unroll
                for (int c = 0; c < 32; c += 2) {
                    aq0 += r1[c]     * xv[c];
                    aq1 += r1[c + 1] * xv[c + 1];
                    ak0 += r2[c]     * xv[c];
                    ak1 += r2[c + 1] * xv[c + 1];
                    av0 += r3[c]     * xv[c];
                    av1 += r3[c + 1] * xv[c + 1];
                }
                oq[oi] += aq0 + aq1;
                ok[oi] += ak0 + ak1;
                ov[oi] += av0 + av1;
            }
        }

        const size_t base = (((size_t)b * 4 + chunk) * HW_ + px) * 16;
        #pragma unroll
        for (int j = 0; j < 4; ++j) {
            *(float4*)(q + base + j * 4) =
                make_float4(oq[j*4], oq[j*4+1], oq[j*4+2], oq[j*4+3]);
            *(float4*)(k + base + j * 4) =
                make_float4(ok[j*4], ok[j*4+1], ok[j*4+2], ok[j*4+3]);
        }
        unsigned vb[8];
        #pragma unroll
        for (int j = 0; j < 8; ++j)
            vb[j] = (unsigned)bfbits(ov[2*j]) | ((unsigned)bfbits(ov[2*j+1]) << 16);
        uint4* vp = (uint4*)(v + base);
        vp[0] = make_uint4(vb[0], vb[1], vb[2], vb[3]);
        vp[1] = make_uint4(vb[4], vb[5], vb[6], vb[7]);
    }
}

// ---------------------------------------------------------------------------
// K2: fused local attention. 16x16 tile, 256 threads, ONE pixel per thread
// (R3's 2-px variant needed ~200 live regs and spilled; this needs ~110).
// LDS plane-major: plane stride 484*4+8=1944 words (bases mod 32 =
// {0,24,16,8}); compute reads are lane-stride-4-word b128 = free 2-way.
// Phase 1: K fp32, 4 planes. Phase 2: V bf16, 2 uint4-planes (half reads).
// grid (8, 8, 8), block 256. LDS 31.1 KB.
// ---------------------------------------------------------------------------
#define HP_ 484                 // 22*22 halo pixels
#define PLANE_ (HP_ * 4 + 8)    // 1944 words per plane

__global__ __launch_bounds__(256, 2) void local_attn(
    const float* __restrict__ q, const float* __restrict__ k,
    const unsigned short* __restrict__ v, float* __restrict__ out)
{
    __shared__ float tile[4 * PLANE_];
    const int b = blockIdx.z, h0 = blockIdx.y * 16, w0 = blockIdx.x * 16;
    const int t = threadIdx.x;
    const int pw = t & 15, ph = t >> 4;

    float sc[49];
    #pragma unroll
    for (int i = 0; i < 49; ++i) sc[i] = 0.f;

    // ---- phase 1: scores (K fp32 in LDS) ----
    for (int chunk = 0; chunk < 4; ++chunk) {
        const float* kc = k + ((size_t)b * 4 + chunk) * HW_ * 16;
        for (int i = t; i < HP_ * 4; i += 256) {
            const int pix = i >> 2, c4 = i & 3;
            const int r = pix / 22, cl = pix - r * 22;
            const int gh = h0 + r - 3, gw = w0 + cl - 3;
            float4 val = make_float4(0.f, 0.f, 0.f, 0.f);
            if (gh >= 0 && gh < H_ && gw >= 0 && gw < W_)
                val = *(const float4*)(kc + ((size_t)gh * W_ + gw) * 16 + c4 * 4);
            *(float4*)(tile + c4 * PLANE_ + pix * 4) = val;
        }
        const float* qp = q + (((size_t)b * 4 + chunk) * HW_ +
                               (size_t)(h0 + ph) * W_ + (w0 + pw)) * 16;
        const float4 q0 = ((const float4*)qp)[0];
        const float4 q1 = ((const float4*)qp)[1];
        const float4 q2 = ((const float4*)qp)[2];
        const float4 q3 = ((const float4*)qp)[3];
        __syncthreads();
        #pragma unroll
        for (int dh = 0; dh < 7; ++dh) {
            #pragma unroll
            for (int dw = 0; dw < 7; ++dw) {
                const int np = ((ph + dh) * 22 + (pw + dw)) * 4;
                const float4 k0 = *(const float4*)(tile + 0 * PLANE_ + np);
                const float4 k1 = *(const float4*)(tile + 1 * PLANE_ + np);
                const float4 k2 = *(const float4*)(tile + 2 * PLANE_ + np);
                const float4 k3 = *(const float4*)(tile + 3 * PLANE_ + np);
                sc[dh * 7 + dw] +=
                    q0.x * k0.x + q0.y * k0.y + q0.z * k0.z + q0.w * k0.w +
                    q1.x * k1.x + q1.y * k1.y + q1.z * k1.z + q1.w * k1.w +
                    q2.x * k2.x + q2.y * k2.y + q2.z * k2.z + q2.w * k2.w +
                    q3.x * k3.x + q3.y * k3.y + q3.z * k3.z + q3.w * k3.w;
            }
        }
        __syncthreads();
    }

    // ---- softmax over 49 ----
    float m = sc[0];
    #pragma unroll
    for (int i = 1; i < 49; ++i) m = fmaxf(m, sc[i]);
    float s = 0.f;
    #pragma unroll
    for (int i = 0; i < 49; ++i) { sc[i] = __expf(sc[i] - m); s += sc[i]; }
    const float inv = 1.f / s;
    #pragma unroll
    for (int i = 0; i < 49; ++i) sc[i] *= inv;

    // ---- phase 2: weighting (V bf16, 2 uint4-planes) ----
    for (int chunk = 0; chunk < 4; ++chunk) {
        const unsigned short* vc = v + ((size_t)b * 4 + chunk) * HW_ * 16;
        for (int i = t; i < HP_ * 2; i += 256) {
            const int pix = i >> 1, c8 = i & 1;
            const int r = pix / 22, cl = pix - r * 22;
            const int gh = h0 + r - 3, gw = w0 + cl - 3;
            uint4 val = make_uint4(0u, 0u, 0u, 0u);
            if (gh >= 0 && gh < H_ && gw >= 0 && gw < W_)
                val = *(const uint4*)(vc + ((size_t)gh * W_ + gw) * 16 + c8 * 8);
            *(uint4*)(tile + c8 * PLANE_ + pix * 4) = val;
        }
        __syncthreads();
        float acc[16];
        #pragma unroll
        for (int c = 0; c < 16; ++c) acc[c] = 0.f;
        #pragma unroll
        for (int dh = 0; dh < 7; ++dh) {
            #pragma unroll
            for (int dw = 0; dw < 7; ++dw) {
                const float wgt = sc[dh * 7 + dw];
                const int np = ((ph + dh) * 22 + (pw + dw)) * 4;
                const uint4 u0 = *(const uint4*)(tile + 0 * PLANE_ + np);
                const uint4 u1 = *(const uint4*)(tile + 1 * PLANE_ + np);
                acc[0]  += wgt * bf_lo(u0.x); acc[1]  += wgt * bf_hi(u0.x);
                acc[2]  += wgt * bf_lo(u0.y); acc[3]  += wgt * bf_hi(u0.y);
                acc[4]  += wgt * bf_lo(u0.z); acc[5]  += wgt * bf_hi(u0.z);
                acc[6]  += wgt * bf_lo(u0.w); acc[7]  += wgt * bf_hi(u0.w);
                acc[8]  += wgt * bf_lo(u1.x); acc[9]  += wgt * bf_hi(u1.x);
                acc[10] += wgt * bf_lo(u1.y); acc[11] += wgt * bf_hi(u1.y);
                acc[12] += wgt * bf_lo(u1.z); acc[13] += wgt * bf_hi(u1.z);
                acc[14] += wgt * bf_lo(u1.w); acc[15] += wgt * bf_hi(u1.w);
            }
        }
        const size_t ob = ((size_t)b * 64 + chunk * 16) * HW_ +
                          (size_t)(h0 + ph) * W_ + (w0 + pw);
        #pragma unroll
        for (int c = 0; c < 16; ++c)
            out[ob + (size_t)c * HW_] = acc[c];
        __syncthreads();
    }
}

extern "C" void kernel_launch(void* const* d_in, const int* in_sizes, int n_in,
                              void* d_out, int out_size, void* d_ws, size_t ws_size,
                              hipStream_t stream) {
    const float* x  = (const float*)d_in[0];
    const float* w1 = (const float*)d_in[1];
    const float* w2 = (const float*)d_in[2];
    const float* w3 = (const float*)d_in[3];

    const size_t NE = (size_t)B_ * 4 * HW_ * 16;
    float* q = (float*)d_ws;
    float* k = q + NE;
    unsigned short* v = (unsigned short*)(k + NE);
    float* o = (float*)d_out;

    proj_qkv<<<dim3(HW_ / 256, B_), 256, 0, stream>>>(x, w1, w2, w3, q, k, v);
    local_attn<<<dim3(W_ / 16, H_ / 16, B_), 256, 0, stream>>>(q, k, v, o);
}

// Round 5
// 209.746 us; speedup vs baseline: 2.6617x; 1.1194x over previous
//
#include <hip/hip_runtime.h>
#include <hip/hip_bf16.h>

#define B_ 8
#define C_ 64
#define H_ 128
#define W_ 128
#define HW_ (H_ * W_)

static __device__ inline unsigned bfbits(float f) {
    __hip_bfloat16 h = __float2bfloat16(f);
    unsigned short s;
    __builtin_memcpy(&s, &h, 2);
    return (unsigned)s;
}
static __device__ inline float bf_lo(unsigned u) { return __uint_as_float(u << 16); }
static __device__ inline float bf_hi(unsigned u) { return __uint_as_float(u & 0xffff0000u); }

// ---------------------------------------------------------------------------
// K0: weight transpose. wT[c][o], o in [0,192): 0-63 W1(q), 64-127 W2(k),
// 128-191 W3(v). Enables wave-uniform s_load streaming in K1.
// ---------------------------------------------------------------------------
__global__ void transpose_w(const float* __restrict__ w1, const float* __restrict__ w2,
                            const float* __restrict__ w3, float* __restrict__ wT)
{
    const int i = blockIdx.x * 256 + threadIdx.x;
    if (i < 192 * 64) {
        const int c = i / 192, o = i - c * 192;
        float val = (o < 64) ? w1[o * 64 + c]
                  : (o < 128) ? w2[(o - 64) * 64 + c]
                  : w3[(o - 128) * 64 + c];
        wT[i] = val;
    }
}

// ---------------------------------------------------------------------------
// K1: QKV projection as a wave-uniform-weight GEMM.
// Block = 64 pixels x 192 outputs, 256 threads (4 waves). Lane = pixel,
// wave w owns outputs o in [48w, 48w+48). Inner loop per c:
//   1 ds_read_b32 (x[c][lane]) + 48 v_fmac with SGPR weight (s_load bcast).
// Only 48 acc VGPRs live -> immune to the compiler's 64-VGPR rematerialize
// trap that made R2-R4 latency-bound. Epilogue transposes acc through LDS
// (stride 65) for coalesced b128 stores; V packed to bf16.
// grid (HW/64=256, B), LDS 16.6 KB.
// ---------------------------------------------------------------------------
__global__ __launch_bounds__(256, 4) void proj_qkv(
    const float* __restrict__ x, const float* __restrict__ wT,
    float* __restrict__ q, float* __restrict__ k, unsigned short* __restrict__ v)
{
    __shared__ float xs[65 * 64];   // staging [c][px] stride 64; epilogue [oc][px] stride 65
    const int b = blockIdx.y;
    const int px0 = blockIdx.x * 64;
    const int t = threadIdx.x;
    const int lane = t & 63;
    const int wgrp = __builtin_amdgcn_readfirstlane(t >> 6);

    // stage x tile: [c][px], wave-uniform c per load, lanes contiguous
    {
        const float* xb = x + (size_t)b * C_ * HW_ + px0;
        #pragma unroll
        for (int i = 0; i < 16; ++i) {
            const int c = i * 4 + (t >> 6);
            xs[c * 64 + lane] = xb[(size_t)c * HW_ + lane];
        }
    }
    __syncthreads();

    float acc[48];
    #pragma unroll
    for (int j = 0; j < 48; ++j) acc[j] = 0.f;

    const float* __restrict__ wbase = wT + wgrp * 48;
    #pragma unroll 1
    for (int c = 0; c < 64; ++c) {
        const float xr = xs[c * 64 + lane];
        const float* __restrict__ wr = wbase + c * 192;   // scalar (wave-uniform) -> s_load
        #pragma unroll
        for (int j = 0; j < 48; ++j) acc[j] = fmaf(wr[j], xr, acc[j]);
    }

    // epilogue: 3 rounds (q fp32, k fp32, v bf16) via LDS transpose
    #pragma unroll
    for (int m = 0; m < 3; ++m) {
        __syncthreads();
        #pragma unroll
        for (int j = 0; j < 48; ++j) {
            const int o = wgrp * 48 + j;
            if (o >= 64 * m && o < 64 * m + 64)
                xs[(o - 64 * m) * 65 + lane] = acc[j];
        }
        __syncthreads();
        const int px = t >> 2, c4 = t & 3;
        float f[16];
        #pragma unroll
        for (int u = 0; u < 16; ++u) f[u] = xs[(c4 * 16 + u) * 65 + px];
        const size_t base = (((size_t)b * 4 + c4) * HW_ + px0 + px) * 16;
        if (m == 0) {
            #pragma unroll
            for (int j2 = 0; j2 < 4; ++j2)
                *(float4*)(q + base + j2 * 4) =
                    make_float4(f[4*j2], f[4*j2+1], f[4*j2+2], f[4*j2+3]);
        } else if (m == 1) {
            #pragma unroll
            for (int j2 = 0; j2 < 4; ++j2)
                *(float4*)(k + base + j2 * 4) =
                    make_float4(f[4*j2], f[4*j2+1], f[4*j2+2], f[4*j2+3]);
        } else {
            unsigned vb[8];
            #pragma unroll
            for (int j2 = 0; j2 < 8; ++j2)
                vb[j2] = bfbits(f[2*j2]) | (bfbits(f[2*j2+1]) << 16);
            uint4* vp = (uint4*)(v + base);
            vp[0] = make_uint4(vb[0], vb[1], vb[2], vb[3]);
            vp[1] = make_uint4(vb[4], vb[5], vb[6], vb[7]);
        }
    }
}

// ---------------------------------------------------------------------------
// K2: fused local attention. 16x16 tile, 256 threads, 1 pixel/thread.
// LDS plane-major (stride 1944 words, bases mod 32 = {0,24,16,8}): compute
// reads are lane-stride-4-word b128 = free 2-way. Phase 1 K fp32 4 planes,
// phase 2 V bf16 2 planes. R5 change: per-neighbor dot is 4 independent
// depth-4 fmaf chains + pairwise sum (fp32-strict forbids reassociation of
// the old 16-deep chain -> was latency-bound at 8 waves/CU).
// grid (8, 8, 8), LDS 31.1 KB.
// ---------------------------------------------------------------------------
#define HP_ 484                 // 22*22 halo pixels
#define PLANE_ (HP_ * 4 + 8)    // 1944 words per plane

__global__ __launch_bounds__(256, 2) void local_attn(
    const float* __restrict__ q, const float* __restrict__ k,
    const unsigned short* __restrict__ v, float* __restrict__ out)
{
    __shared__ float tile[4 * PLANE_];
    const int b = blockIdx.z, h0 = blockIdx.y * 16, w0 = blockIdx.x * 16;
    const int t = threadIdx.x;
    const int pw = t & 15, ph = t >> 4;

    float sc[49];
    #pragma unroll
    for (int i = 0; i < 49; ++i) sc[i] = 0.f;

    // ---- phase 1: scores (K fp32 in LDS) ----
    for (int chunk = 0; chunk < 4; ++chunk) {
        const float* kc = k + ((size_t)b * 4 + chunk) * HW_ * 16;
        for (int i = t; i < HP_ * 4; i += 256) {
            const int pix = i >> 2, c4 = i & 3;
            const int r = pix / 22, cl = pix - r * 22;
            const int gh = h0 + r - 3, gw = w0 + cl - 3;
            float4 val = make_float4(0.f, 0.f, 0.f, 0.f);
            if (gh >= 0 && gh < H_ && gw >= 0 && gw < W_)
                val = *(const float4*)(kc + ((size_t)gh * W_ + gw) * 16 + c4 * 4);
            *(float4*)(tile + c4 * PLANE_ + pix * 4) = val;
        }
        const float* qp = q + (((size_t)b * 4 + chunk) * HW_ +
                               (size_t)(h0 + ph) * W_ + (w0 + pw)) * 16;
        const float4 q0 = ((const float4*)qp)[0];
        const float4 q1 = ((const float4*)qp)[1];
        const float4 q2 = ((const float4*)qp)[2];
        const float4 q3 = ((const float4*)qp)[3];
        __syncthreads();
        #pragma unroll
        for (int dh = 0; dh < 7; ++dh) {
            #pragma unroll
            for (int dw = 0; dw < 7; ++dw) {
                const int np = ((ph + dh) * 22 + (pw + dw)) * 4;
                const float4 k0 = *(const float4*)(tile + 0 * PLANE_ + np);
                const float4 k1 = *(const float4*)(tile + 1 * PLANE_ + np);
                const float4 k2 = *(const float4*)(tile + 2 * PLANE_ + np);
                const float4 k3 = *(const float4*)(tile + 3 * PLANE_ + np);
                float d0 = fmaf(q0.w, k0.w, fmaf(q0.z, k0.z, fmaf(q0.y, k0.y, q0.x * k0.x)));
                float d1 = fmaf(q1.w, k1.w, fmaf(q1.z, k1.z, fmaf(q1.y, k1.y, q1.x * k1.x)));
                float d2 = fmaf(q2.w, k2.w, fmaf(q2.z, k2.z, fmaf(q2.y, k2.y, q2.x * k2.x)));
                float d3 = fmaf(q3.w, k3.w, fmaf(q3.z, k3.z, fmaf(q3.y, k3.y, q3.x * k3.x)));
                sc[dh * 7 + dw] += (d0 + d1) + (d2 + d3);
            }
        }
        __syncthreads();
    }

    // ---- softmax over 49 ----
    float m = sc[0];
    #pragma unroll
    for (int i = 1; i < 49; ++i) m = fmaxf(m, sc[i]);
    float s = 0.f;
    #pragma unroll
    for (int i = 0; i < 49; ++i) { sc[i] = __expf(sc[i] - m); s += sc[i]; }
    const float inv = 1.f / s;
    #pragma unroll
    for (int i = 0; i < 49; ++i) sc[i] *= inv;

    // ---- phase 2: weighting (V bf16, 2 uint4-planes) ----
    for (int chunk = 0; chunk < 4; ++chunk) {
        const unsigned short* vc = v + ((size_t)b * 4 + chunk) * HW_ * 16;
        for (int i = t; i < HP_ * 2; i += 256) {
            const int pix = i >> 1, c8 = i & 1;
            const int r = pix / 22, cl = pix - r * 22;
            const int gh = h0 + r - 3, gw = w0 + cl - 3;
            uint4 val = make_uint4(0u, 0u, 0u, 0u);
            if (gh >= 0 && gh < H_ && gw >= 0 && gw < W_)
                val = *(const uint4*)(vc + ((size_t)gh * W_ + gw) * 16 + c8 * 8);
            *(uint4*)(tile + c8 * PLANE_ + pix * 4) = val;
        }
        __syncthreads();
        float acc[16];
        #pragma unroll
        for (int c = 0; c < 16; ++c) acc[c] = 0.f;
        #pragma unroll
        for (int dh = 0; dh < 7; ++dh) {
            #pragma unroll
            for (int dw = 0; dw < 7; ++dw) {
                const float wgt = sc[dh * 7 + dw];
                const int np = ((ph + dh) * 22 + (pw + dw)) * 4;
                const uint4 u0 = *(const uint4*)(tile + 0 * PLANE_ + np);
                const uint4 u1 = *(const uint4*)(tile + 1 * PLANE_ + np);
                acc[0]  = fmaf(wgt, bf_lo(u0.x), acc[0]);  acc[1]  = fmaf(wgt, bf_hi(u0.x), acc[1]);
                acc[2]  = fmaf(wgt, bf_lo(u0.y), acc[2]);  acc[3]  = fmaf(wgt, bf_hi(u0.y), acc[3]);
                acc[4]  = fmaf(wgt, bf_lo(u0.z), acc[4]);  acc[5]  = fmaf(wgt, bf_hi(u0.z), acc[5]);
                acc[6]  = fmaf(wgt, bf_lo(u0.w), acc[6]);  acc[7]  = fmaf(wgt, bf_hi(u0.w), acc[7]);
                acc[8]  = fmaf(wgt, bf_lo(u1.x), acc[8]);  acc[9]  = fmaf(wgt, bf_hi(u1.x), acc[9]);
                acc[10] = fmaf(wgt, bf_lo(u1.y), acc[10]); acc[11] = fmaf(wgt, bf_hi(u1.y), acc[11]);
                acc[12] = fmaf(wgt, bf_lo(u1.z), acc[12]); acc[13] = fmaf(wgt, bf_hi(u1.z), acc[13]);
                acc[14] = fmaf(wgt, bf_lo(u1.w), acc[14]); acc[15] = fmaf(wgt, bf_hi(u1.w), acc[15]);
            }
        }
        const size_t ob = ((size_t)b * 64 + chunk * 16) * HW_ +
                          (size_t)(h0 + ph) * W_ + (w0 + pw);
        #pragma unroll
        for (int c = 0; c < 16; ++c)
            out[ob + (size_t)c * HW_] = acc[c];
        __syncthreads();
    }
}

extern "C" void kernel_launch(void* const* d_in, const int* in_sizes, int n_in,
                              void* d_out, int out_size, void* d_ws, size_t ws_size,
                              hipStream_t stream) {
    const float* x  = (const float*)d_in[0];
    const float* w1 = (const float*)d_in[1];
    const float* w2 = (const float*)d_in[2];
    const float* w3 = (const float*)d_in[3];

    const size_t NE = (size_t)B_ * 4 * HW_ * 16;   // 8388608
    float* q = (float*)d_ws;
    float* k = q + NE;
    unsigned short* v = (unsigned short*)(k + NE);
    float* wT = (float*)(v + NE);                  // 12288 floats
    float* o = (float*)d_out;

    transpose_w<<<dim3(48), 256, 0, stream>>>(w1, w2, w3, wT);
    proj_qkv<<<dim3(HW_ / 64, B_), 256, 0, stream>>>(x, wT, q, k, v);
    local_attn<<<dim3(W_ / 16, H_ / 16, B_), 256, 0, stream>>>(q, k, v, o);
}

// Round 7
// 175.103 us; speedup vs baseline: 3.1883x; 1.1978x over previous
//
#include <hip/hip_runtime.h>
#include <hip/hip_bf16.h>

#define B_ 8
#define C_ 64
#define H_ 128
#define W_ 128
#define HW_ (H_ * W_)

typedef __attribute__((ext_vector_type(8))) short short8;
typedef __attribute__((ext_vector_type(4))) float float4v;

static __device__ inline unsigned bfbits(float f) {
    __hip_bfloat16 h = __float2bfloat16(f);
    unsigned short s;
    __builtin_memcpy(&s, &h, 2);
    return (unsigned)s;
}
static __device__ inline float bf_lo(unsigned u) { return __uint_as_float(u << 16); }
static __device__ inline float bf_hi(unsigned u) { return __uint_as_float(u & 0xffff0000u); }

// ---------------------------------------------------------------------------
// K0: repack W1|W2|W3 (fp32 [o][c]) into bf16 MFMA B-fragments, SPLIT hi/lo
// (W = Wh + Wl, each bf16) so the proj GEMM is fp32-grade (R6's single-bf16
// W cost ~0.03 score error and busted the threshold).
// Index: wB*[((nt*2+ks)*64+lane)*8+j] = W[o=nt*16+(lane&15)][c=ks*32+(lane>>4)*8+j]
// ---------------------------------------------------------------------------
__global__ void repack_w(const float* __restrict__ w1, const float* __restrict__ w2,
                         const float* __restrict__ w3,
                         unsigned short* __restrict__ wBhi, unsigned short* __restrict__ wBlo)
{
    const int i = blockIdx.x * 256 + threadIdx.x;
    if (i >= 12288) return;
    const int j = i & 7, lane = (i >> 3) & 63, ks = (i >> 9) & 1, nt = i >> 10;
    const int o = nt * 16 + (lane & 15);
    const int c = ks * 32 + (lane >> 4) * 8 + j;
    const float* wsel = (o < 64) ? w1 : (o < 128) ? w2 : w3;
    const float w = wsel[(o & 63) * 64 + c];
    const unsigned hb = bfbits(w);
    wBhi[i] = (unsigned short)hb;
    wBlo[i] = (unsigned short)bfbits(w - __uint_as_float(hb << 16));
}

// ---------------------------------------------------------------------------
// K1: QKV projection as bf16 MFMA GEMM, fp32-grade via 3-term split:
// x*W = xh*Wh + xl*Wh + xh*Wl  (xl*Wl ~ 2^-18, dropped).
// M=px, N=192, K=64. Block 128px x 192out, 4 waves 2x2. Per wave: 4 m-tiles
// x 6 n-tiles, 2 K-steps, 3 MFMAs each = 144 MFMA. A direct from global;
// B loaded per (tile,ks) from L2 (transient 8 regs). Live regs ~150:
// 96 acc + 32 A + 8 B -- no scalar arrays to spill (R2-R5 lesson).
// q fp32, k fp32 (R6's bf16 k busted precision), v bf16. [B][4][HW][16].
// grid (HW/128=128, B). No LDS.
// ---------------------------------------------------------------------------
__global__ __launch_bounds__(256, 2) void proj_qkv(
    const float* __restrict__ x,
    const unsigned short* __restrict__ wBhi, const unsigned short* __restrict__ wBlo,
    float* __restrict__ q, float* __restrict__ k, unsigned short* __restrict__ v)
{
    const int b = blockIdx.y;
    const int px0 = blockIdx.x * 128;
    const int t = threadIdx.x;
    const int lane = t & 63;
    const int wave_m = (t >> 6) & 1, wave_n = t >> 7;
    const int n = lane & 15, kg = lane >> 4;

    float4v acc[6][4];
    #pragma unroll
    for (int tnt = 0; tnt < 6; ++tnt)
        #pragma unroll
        for (int mt = 0; mt < 4; ++mt)
            acc[tnt][mt] = (float4v){0.f, 0.f, 0.f, 0.f};

    const float* xb = x + (size_t)b * C_ * HW_;
    const int pxl = px0 + wave_m * 64 + n;

    #pragma unroll
    for (int ks = 0; ks < 2; ++ks) {
        short8 ahi[4], alo[4];
        #pragma unroll
        for (int mt = 0; mt < 4; ++mt) {
            #pragma unroll
            for (int j = 0; j < 8; ++j) {
                const int c = ks * 32 + kg * 8 + j;
                const float f = xb[(size_t)c * HW_ + pxl + mt * 16];
                const unsigned hb = bfbits(f);
                ahi[mt][j] = (short)hb;
                alo[mt][j] = (short)bfbits(f - __uint_as_float(hb << 16));
            }
        }
        #pragma unroll
        for (int tnt = 0; tnt < 6; ++tnt) {
            const size_t bidx = (((size_t)(wave_n * 6 + tnt) * 2 + ks) * 64 + lane) * 8;
            short8 bh, bl;
            {
                const uint4 uh = *(const uint4*)(wBhi + bidx);
                const uint4 ul = *(const uint4*)(wBlo + bidx);
                __builtin_memcpy(&bh, &uh, 16);
                __builtin_memcpy(&bl, &ul, 16);
            }
            #pragma unroll
            for (int mt = 0; mt < 4; ++mt) {
                acc[tnt][mt] = __builtin_amdgcn_mfma_f32_16x16x32_bf16(
                    ahi[mt], bh, acc[tnt][mt], 0, 0, 0);
                acc[tnt][mt] = __builtin_amdgcn_mfma_f32_16x16x32_bf16(
                    alo[mt], bh, acc[tnt][mt], 0, 0, 0);
                acc[tnt][mt] = __builtin_amdgcn_mfma_f32_16x16x32_bf16(
                    ahi[mt], bl, acc[tnt][mt], 0, 0, 0);
            }
        }
    }

    // epilogue: D col = n (output o), row m = kg*4 + reg (pixel)
    #pragma unroll
    for (int tnt = 0; tnt < 6; ++tnt) {
        const int o_base = wave_n * 96 + tnt * 16;   // wave-uniform
        #pragma unroll
        for (int mt = 0; mt < 4; ++mt) {
            const int pxm = px0 + wave_m * 64 + mt * 16 + kg * 4;
            const float4v d = acc[tnt][mt];
            if (o_base < 64) {
                const int chunk = o_base >> 4;
                float* p = q + (((size_t)b * 4 + chunk) * HW_ + pxm) * 16 + n;
                #pragma unroll
                for (int r = 0; r < 4; ++r) p[(size_t)r * 16] = d[r];
            } else if (o_base < 128) {
                const int chunk = (o_base - 64) >> 4;
                float* p = k + (((size_t)b * 4 + chunk) * HW_ + pxm) * 16 + n;
                #pragma unroll
                for (int r = 0; r < 4; ++r) p[(size_t)r * 16] = d[r];
            } else {
                const int chunk = (o_base - 128) >> 4;
                unsigned short* p = v + (((size_t)b * 4 + chunk) * HW_ + pxm) * 16 + n;
                #pragma unroll
                for (int r = 0; r < 4; ++r) p[(size_t)r * 16] = (unsigned short)bfbits(d[r]);
            }
        }
    }
}

// ---------------------------------------------------------------------------
// K2: fused local attention (R5's known-good kernel, absmax 0.031 @ 72us).
// 16x16 tile, 1 px/thread. Phase 1: K fp32, 4 planes. Phase 2: V bf16,
// 2 planes. Plane stride 1944 words (bases mod 32 = {0,24,16,8}); compute
// reads lane-stride-4-word b128 = free 2-way. Independent fmaf chains.
// grid (8, 8, 8), LDS 31.1 KB.
// ---------------------------------------------------------------------------
#define HP_ 484                 // 22*22 halo pixels
#define PLANE_ (HP_ * 4 + 8)    // 1944 words per plane

__global__ __launch_bounds__(256, 2) void local_attn(
    const float* __restrict__ q, const float* __restrict__ k,
    const unsigned short* __restrict__ v, float* __restrict__ out)
{
    __shared__ float tile[4 * PLANE_];
    const int b = blockIdx.z, h0 = blockIdx.y * 16, w0 = blockIdx.x * 16;
    const int t = threadIdx.x;
    const int pw = t & 15, ph = t >> 4;

    float sc[49];
    #pragma unroll
    for (int i = 0; i < 49; ++i) sc[i] = 0.f;

    // ---- phase 1: scores (K fp32 in LDS) ----
    for (int chunk = 0; chunk < 4; ++chunk) {
        const float* kc = k + ((size_t)b * 4 + chunk) * HW_ * 16;
        for (int i = t; i < HP_ * 4; i += 256) {
            const int pix = i >> 2, c4 = i & 3;
            const int r = pix / 22, cl = pix - r * 22;
            const int gh = h0 + r - 3, gw = w0 + cl - 3;
            float4 val = make_float4(0.f, 0.f, 0.f, 0.f);
            if (gh >= 0 && gh < H_ && gw >= 0 && gw < W_)
                val = *(const float4*)(kc + ((size_t)gh * W_ + gw) * 16 + c4 * 4);
            *(float4*)(tile + c4 * PLANE_ + pix * 4) = val;
        }
        const float* qp = q + (((size_t)b * 4 + chunk) * HW_ +
                               (size_t)(h0 + ph) * W_ + (w0 + pw)) * 16;
        const float4 q0 = ((const float4*)qp)[0];
        const float4 q1 = ((const float4*)qp)[1];
        const float4 q2 = ((const float4*)qp)[2];
        const float4 q3 = ((const float4*)qp)[3];
        __syncthreads();
        #pragma unroll
        for (int dh = 0; dh < 7; ++dh) {
            #pragma unroll
            for (int dw = 0; dw < 7; ++dw) {
                const int np = ((ph + dh) * 22 + (pw + dw)) * 4;
                const float4 k0 = *(const float4*)(tile + 0 * PLANE_ + np);
                const float4 k1 = *(const float4*)(tile + 1 * PLANE_ + np);
                const float4 k2 = *(const float4*)(tile + 2 * PLANE_ + np);
                const float4 k3 = *(const float4*)(tile + 3 * PLANE_ + np);
                float d0 = fmaf(q0.w, k0.w, fmaf(q0.z, k0.z, fmaf(q0.y, k0.y, q0.x * k0.x)));
                float d1 = fmaf(q1.w, k1.w, fmaf(q1.z, k1.z, fmaf(q1.y, k1.y, q1.x * k1.x)));
                float d2 = fmaf(q2.w, k2.w, fmaf(q2.z, k2.z, fmaf(q2.y, k2.y, q2.x * k2.x)));
                float d3 = fmaf(q3.w, k3.w, fmaf(q3.z, k3.z, fmaf(q3.y, k3.y, q3.x * k3.x)));
                sc[dh * 7 + dw] += (d0 + d1) + (d2 + d3);
            }
        }
        __syncthreads();
    }

    // ---- softmax over 49 ----
    float m = sc[0];
    #pragma unroll
    for (int i = 1; i < 49; ++i) m = fmaxf(m, sc[i]);
    float s = 0.f;
    #pragma unroll
    for (int i = 0; i < 49; ++i) { sc[i] = __expf(sc[i] - m); s += sc[i]; }
    const float inv = 1.f / s;
    #pragma unroll
    for (int i = 0; i < 49; ++i) sc[i] *= inv;

    // ---- phase 2: weighting (V bf16, 2 uint4-planes) ----
    for (int chunk = 0; chunk < 4; ++chunk) {
        const unsigned short* vc = v + ((size_t)b * 4 + chunk) * HW_ * 16;
        for (int i = t; i < HP_ * 2; i += 256) {
            const int pix = i >> 1, c8 = i & 1;
            const int r = pix / 22, cl = pix - r * 22;
            const int gh = h0 + r - 3, gw = w0 + cl - 3;
            uint4 val = make_uint4(0u, 0u, 0u, 0u);
            if (gh >= 0 && gh < H_ && gw >= 0 && gw < W_)
                val = *(const uint4*)(vc + ((size_t)gh * W_ + gw) * 16 + c8 * 8);
            *(uint4*)(tile + c8 * PLANE_ + pix * 4) = val;
        }
        __syncthreads();
        float acc[16];
        #pragma unroll
        for (int c = 0; c < 16; ++c) acc[c] = 0.f;
        #pragma unroll
        for (int dh = 0; dh < 7; ++dh) {
            #pragma unroll
            for (int dw = 0; dw < 7; ++dw) {
                const float wgt = sc[dh * 7 + dw];
                const int np = ((ph + dh) * 22 + (pw + dw)) * 4;
                const uint4 u0 = *(const uint4*)(tile + 0 * PLANE_ + np);
                const uint4 u1 = *(const uint4*)(tile + 1 * PLANE_ + np);
                acc[0]  = fmaf(wgt, bf_lo(u0.x), acc[0]);  acc[1]  = fmaf(wgt, bf_hi(u0.x), acc[1]);
                acc[2]  = fmaf(wgt, bf_lo(u0.y), acc[2]);  acc[3]  = fmaf(wgt, bf_hi(u0.y), acc[3]);
                acc[4]  = fmaf(wgt, bf_lo(u0.z), acc[4]);  acc[5]  = fmaf(wgt, bf_hi(u0.z), acc[5]);
                acc[6]  = fmaf(wgt, bf_lo(u0.w), acc[6]);  acc[7]  = fmaf(wgt, bf_hi(u0.w), acc[7]);
                acc[8]  = fmaf(wgt, bf_lo(u1.x), acc[8]);  acc[9]  = fmaf(wgt, bf_hi(u1.x), acc[9]);
                acc[10] = fmaf(wgt, bf_lo(u1.y), acc[10]); acc[11] = fmaf(wgt, bf_hi(u1.y), acc[11]);
                acc[12] = fmaf(wgt, bf_lo(u1.z), acc[12]); acc[13] = fmaf(wgt, bf_hi(u1.z), acc[13]);
                acc[14] = fmaf(wgt, bf_lo(u1.w), acc[14]); acc[15] = fmaf(wgt, bf_hi(u1.w), acc[15]);
            }
        }
        const size_t ob = ((size_t)b * 64 + chunk * 16) * HW_ +
                          (size_t)(h0 + ph) * W_ + (w0 + pw);
        #pragma unroll
        for (int c = 0; c < 16; ++c)
            out[ob + (size_t)c * HW_] = acc[c];
        __syncthreads();
    }
}

extern "C" void kernel_launch(void* const* d_in, const int* in_sizes, int n_in,
                              void* d_out, int out_size, void* d_ws, size_t ws_size,
                              hipStream_t stream) {
    const float* x  = (const float*)d_in[0];
    const float* w1 = (const float*)d_in[1];
    const float* w2 = (const float*)d_in[2];
    const float* w3 = (const float*)d_in[3];

    const size_t NE = (size_t)B_ * 4 * HW_ * 16;   // 8388608
    float* q = (float*)d_ws;
    float* k = q + NE;
    unsigned short* v = (unsigned short*)(k + NE);
    unsigned short* wBhi = v + NE;                 // 12288 ushorts
    unsigned short* wBlo = wBhi + 12288;
    float* o = (float*)d_out;

    repack_w<<<dim3(48), 256, 0, stream>>>(w1, w2, w3, wBhi, wBlo);
    proj_qkv<<<dim3(HW_ / 128, B_), 256, 0, stream>>>(x, wBhi, wBlo, q, k, v);
    local_attn<<<dim3(W_ / 16, H_ / 16, B_), 256, 0, stream>>>(q, k, v, o);
}